// Round 1
// baseline (981.933 us; speedup 1.0000x reference)
//
#include <hip/hip_runtime.h>
#include <stdint.h>

#define N_PTS 4096
#define B_SZ 8
#define D_DIM 64
#define KNN 20
#define NROWS (B_SZ * N_PTS)   // 32768
#define C_CHUNKS 4
#define CHUNK (N_PTS / C_CHUNKS)  // 1024
#define H1C 32
#define H2C 64
#define BN_EPS 1e-3f

// ---------------------------------------------------------------- K1: sq[row]
__global__ void sq_kernel(const float* __restrict__ x, float* __restrict__ sq) {
    int row = blockIdx.x * blockDim.x + threadIdx.x;
    if (row >= NROWS) return;
    const float4* xr = (const float4*)(x + (size_t)row * D_DIM);
    float acc = 0.f;
#pragma unroll
    for (int q = 0; q < 16; ++q) {
        float4 v = xr[q];
        acc = fmaf(v.x, v.x, acc);
        acc = fmaf(v.y, v.y, acc);
        acc = fmaf(v.z, v.z, acc);
        acc = fmaf(v.w, v.w, acc);
    }
    sq[row] = acc;
}

// ------------------------------------------------- K2: fused dist + partial topk
// grid (NROWS/256, C_CHUNKS), block 256. Thread owns one query row, one j-chunk.
__global__ __launch_bounds__(256, 2) void knn_partial(
    const float* __restrict__ x, const float* __restrict__ sq,
    unsigned long long* __restrict__ part) {
    __shared__ float xj[64][64];
    __shared__ float sqj[64];

    int row = blockIdx.x * 256 + threadIdx.x;   // global row
    int b = row >> 12;
    int chunk = blockIdx.y;
    const float* xb = x + (size_t)b * N_PTS * D_DIM;
    const float* sqb = sq + (size_t)b * N_PTS;

    float4 xi[16];
    {
        const float4* xr = (const float4*)(x + (size_t)row * D_DIM);
#pragma unroll
        for (int q = 0; q < 16; ++q) xi[q] = xr[q];
    }
    float sqi = sq[row];

    unsigned long long top[KNN];
#pragma unroll
    for (int p = 0; p < KNN; ++p) top[p] = ~0ull;

    int j0base = chunk * CHUNK;
    for (int t = 0; t < CHUNK / 64; ++t) {
        int j0 = j0base + t * 64;
        __syncthreads();
        {   // stage 64 rows x 64 floats (16KB), coalesced
            const float4* src = (const float4*)(xb + (size_t)j0 * D_DIM);
            float4* dst = (float4*)(&xj[0][0]);
#pragma unroll
            for (int q = 0; q < 4; ++q)
                dst[threadIdx.x + 256 * q] = src[threadIdx.x + 256 * q];
            if (threadIdx.x < 16)
                ((float4*)sqj)[threadIdx.x] = ((const float4*)(sqb + j0))[threadIdx.x];
        }
        __syncthreads();
#pragma unroll 4
        for (int jj = 0; jj < 64; ++jj) {
            const float4* xjr = (const float4*)(&xj[jj][0]);
            float acc = 0.f;
#pragma unroll
            for (int q = 0; q < 16; ++q) {
                float4 vb = xjr[q];
                acc = fmaf(xi[q].x, vb.x, acc);
                acc = fmaf(xi[q].y, vb.y, acc);
                acc = fmaf(xi[q].z, vb.z, acc);
                acc = fmaf(xi[q].w, vb.w, acc);
            }
            // match reference rounding shape: (sq_i - 2*inner) + sq_j ; >= 0
            float d = (sqi - 2.f * acc) + sqj[jj];
            int j = j0 + jj;
            unsigned long long key =
                (((unsigned long long)__float_as_uint(d)) << 32) | (unsigned)j;
            if (key < top[KNN - 1]) {
#pragma unroll
                for (int p = KNN - 1; p >= 1; --p) {
                    unsigned long long prev = top[p - 1];
                    top[p] = (prev > key) ? prev : ((top[p] > key) ? key : top[p]);
                }
                top[0] = (top[0] > key) ? key : top[0];
            }
        }
    }
    // coalesced: part[(chunk*KNN+p)*NROWS + row]
#pragma unroll
    for (int p = 0; p < KNN; ++p)
        part[((size_t)(chunk * KNN + p)) * NROWS + row] = top[p];
}

// ---------------------------------------------------------- K3: merge partials
__global__ void knn_merge(const unsigned long long* __restrict__ part,
                          int* __restrict__ knn) {
    int row = blockIdx.x * blockDim.x + threadIdx.x;
    if (row >= NROWS) return;
    unsigned long long top[KNN];
#pragma unroll
    for (int q = 0; q < KNN; ++q) top[q] = ~0ull;
    for (int s = 0; s < C_CHUNKS * KNN; ++s) {
        unsigned long long key = part[(size_t)s * NROWS + row];
        if (key < top[KNN - 1]) {
#pragma unroll
            for (int q = KNN - 1; q >= 1; --q) {
                unsigned long long prev = top[q - 1];
                top[q] = (prev > key) ? prev : ((top[q] > key) ? key : top[q]);
            }
            top[0] = (top[0] > key) ? key : top[0];
        }
    }
#pragma unroll
    for (int q = 0; q < KNN; ++q)
        knn[(size_t)q * NROWS + row] = (int)(unsigned)(top[q] & 0xffffffffu);
}

// ------------------------------------- K4: edge-feature max + MLP1 (128->32) + relu
// block 256 = 4 waves = 4 rows; lane d handles dim d of the gather/max.
__global__ void edge_mlp1(const float* __restrict__ x, const int* __restrict__ knn,
                          const float* __restrict__ w1, const float* __restrict__ b1,
                          float* __restrict__ h1) {
    __shared__ float w1t[H1C][132];   // transposed, padded (16B-aligned rows)
    __shared__ float feat[4][128];
    int tid = threadIdx.x;
    int wave = tid >> 6, lane = tid & 63;
    for (int idx = tid; idx < 128 * H1C; idx += 256) {
        int f = idx >> 5, c = idx & 31;
        w1t[c][f] = w1[idx];
    }
    int row = blockIdx.x * 4 + wave;
    int b = row >> 12;
    int n = row & (N_PTS - 1);
    const float* xb = x + (size_t)b * N_PTS * D_DIM;
    float central = xb[(size_t)n * D_DIM + lane];
    float m = -1e30f;
    for (int k = 0; k < KNN; ++k) {
        int j = knn[(size_t)k * NROWS + row];
        float xn = xb[(size_t)j * D_DIM + lane];
        m = fmaxf(m, xn - central);
    }
    feat[wave][lane] = central;        // max over K of broadcast central = central
    feat[wave][64 + lane] = m;
    __syncthreads();
    if (lane < H1C) {
        int c = lane;
        float acc = b1[c];
#pragma unroll
        for (int fq = 0; fq < 32; ++fq) {
            float4 fv = *(const float4*)(&feat[wave][fq * 4]);
            float4 wv = *(const float4*)(&w1t[c][fq * 4]);
            acc = fmaf(fv.x, wv.x, acc);
            acc = fmaf(fv.y, wv.y, acc);
            acc = fmaf(fv.z, wv.z, acc);
            acc = fmaf(fv.w, wv.w, acc);
        }
        h1[(size_t)row * H1C + c] = fmaxf(acc, 0.f);
    }
}

// ------------------------------------------------- K5/K7: BN stats (sum, sumsq)
template <int CH>
__global__ void stats_kernel(const float* __restrict__ h, float* __restrict__ sum,
                             float* __restrict__ sumsq) {
    const int RPI = 256 / CH;
    int tid = threadIdx.x;
    int c = tid % CH;
    int r0 = tid / CH;
    float s = 0.f, s2 = 0.f;
    for (int r = blockIdx.x * RPI + r0; r < NROWS; r += gridDim.x * RPI) {
        float v = h[(size_t)r * CH + c];
        s += v;
        s2 = fmaf(v, v, s2);
    }
    __shared__ float ls[256], ls2[256];
    ls[tid] = s; ls2[tid] = s2;
    __syncthreads();
    for (int step = 128; step >= CH; step >>= 1) {
        if (tid < step) { ls[tid] += ls[tid + step]; ls2[tid] += ls2[tid + step]; }
        __syncthreads();
    }
    if (tid < CH) {
        atomicAdd(&sum[tid], ls[tid]);
        atomicAdd(&sumsq[tid], ls2[tid]);
    }
}

template <int CH>
__global__ void coeff_kernel(const float* sum, const float* sumsq, const float* g,
                             const float* be, float* a, float* cc) {
    int c = threadIdx.x;
    if (c >= CH) return;
    float mean = sum[c] * (1.f / NROWS);
    float var = sumsq[c] * (1.f / NROWS) - mean * mean;
    float aa = g[c] * rsqrtf(var + BN_EPS);
    a[c] = aa;
    cc[c] = be[c] - aa * mean;
}

// ------------------------------------------------- K6: BN1-apply + MLP2 + relu
__global__ void mlp2_kernel(const float* __restrict__ h1, const float* __restrict__ w2,
                            const float* __restrict__ b2, const float* __restrict__ a1,
                            const float* __restrict__ c1, float* __restrict__ h2) {
    __shared__ float w2s[H1C][H2C];
    __shared__ float hb[4][H1C];
    int tid = threadIdx.x;
    for (int idx = tid; idx < H1C * H2C; idx += 256)
        w2s[idx >> 6][idx & 63] = w2[idx];
    int rw = tid >> 6;
    int c = tid & 63;
    int row = blockIdx.x * 4 + rw;
    if (c < H1C) {
        float v = h1[(size_t)row * H1C + c];
        hb[rw][c] = fmaf(a1[c], v, c1[c]);
    }
    __syncthreads();
    float acc = b2[c];
#pragma unroll
    for (int f = 0; f < H1C; ++f)
        acc = fmaf(hb[rw][f], w2s[f][c], acc);
    h2[(size_t)row * H2C + c] = fmaxf(acc, 0.f);
}

// ------------------------------------------------- K8: partial max/min over N
__global__ void pool_part(const float* __restrict__ h2, float* __restrict__ pmax,
                          float* __restrict__ pmin) {
    int bb = blockIdx.x >> 3;
    int ch = blockIdx.x & 7;
    int tid = threadIdx.x;
    int rw = tid >> 6, c = tid & 63;
    float mx = -1e30f, mn = 1e30f;
    const float* hbase = h2 + (size_t)bb * N_PTS * H2C;
    for (int n = ch * 512 + rw; n < (ch + 1) * 512; n += 4) {
        float v = hbase[(size_t)n * H2C + c];
        mx = fmaxf(mx, v);
        mn = fminf(mn, v);
    }
    __shared__ float smx[256], smn[256];
    smx[tid] = mx; smn[tid] = mn;
    __syncthreads();
    if (tid < 128) { smx[tid] = fmaxf(smx[tid], smx[tid + 128]); smn[tid] = fminf(smn[tid], smn[tid + 128]); }
    __syncthreads();
    if (tid < 64) {
        pmax[((size_t)bb * 8 + ch) * 64 + tid] = fmaxf(smx[tid], smx[tid + 64]);
        pmin[((size_t)bb * 8 + ch) * 64 + tid] = fminf(smn[tid], smn[tid + 64]);
    }
}

// ------------------------------------------------- K9: final pool + BN2 apply
__global__ void pool_final(const float* pmax, const float* pmin, const float* a2,
                           const float* c2, float* pooled) {
    int bb = blockIdx.x;
    int c = threadIdx.x;
    float M = -1e30f, m = 1e30f;
    for (int ch = 0; ch < 8; ++ch) {
        M = fmaxf(M, pmax[((size_t)bb * 8 + ch) * 64 + c]);
        m = fminf(m, pmin[((size_t)bb * 8 + ch) * 64 + c]);
    }
    float aa = a2[c];
    pooled[bb * 64 + c] = (aa >= 0.f) ? fmaf(aa, M, c2[c]) : fmaf(aa, m, c2[c]);
}

// ------------------------------------------------- K10: head GEMV + softmax
__global__ __launch_bounds__(1024) void head_kernel(const float* __restrict__ pooled,
                                                    const float* __restrict__ wd,
                                                    const float* __restrict__ bd,
                                                    float* __restrict__ out) {
    int bb = blockIdx.x;
    int tid = threadIdx.x;
    __shared__ float pl[64];
    __shared__ float red[1024];
    if (tid < 64) pl[tid] = pooled[bb * 64 + tid];
    __syncthreads();
    float logit[4];
#pragma unroll
    for (int q = 0; q < 4; ++q) {
        int mcol = tid + q * 1024;
        float acc = bd[mcol];
#pragma unroll
        for (int c = 0; c < 64; ++c)
            acc = fmaf(pl[c], wd[(size_t)c * N_PTS + mcol], acc);
        logit[q] = acc;
    }
    float mx = fmaxf(fmaxf(logit[0], logit[1]), fmaxf(logit[2], logit[3]));
    red[tid] = mx;
    __syncthreads();
    for (int s = 512; s >= 1; s >>= 1) {
        if (tid < s) red[tid] = fmaxf(red[tid], red[tid + s]);
        __syncthreads();
    }
    float gmax = red[0];
    __syncthreads();
    float e[4];
    float ssum = 0.f;
#pragma unroll
    for (int q = 0; q < 4; ++q) { e[q] = __expf(logit[q] - gmax); ssum += e[q]; }
    red[tid] = ssum;
    __syncthreads();
    for (int s = 512; s >= 1; s >>= 1) {
        if (tid < s) red[tid] += red[tid + s];
        __syncthreads();
    }
    float inv = 1.f / red[0];
#pragma unroll
    for (int q = 0; q < 4; ++q)
        out[(size_t)bb * N_PTS + tid + q * 1024] = e[q] * inv;
}

// -----------------------------------------------------------------------------
extern "C" void kernel_launch(void* const* d_in, const int* in_sizes, int n_in,
                              void* d_out, int out_size, void* d_ws, size_t ws_size,
                              hipStream_t stream) {
    (void)in_sizes; (void)n_in; (void)out_size; (void)ws_size;
    const float* x   = (const float*)d_in[0];
    const float* w1  = (const float*)d_in[1];
    const float* b1  = (const float*)d_in[2];
    const float* g1  = (const float*)d_in[3];
    const float* be1 = (const float*)d_in[4];
    const float* w2  = (const float*)d_in[5];
    const float* b2  = (const float*)d_in[6];
    const float* g2  = (const float*)d_in[7];
    const float* be2 = (const float*)d_in[8];
    const float* wd  = (const float*)d_in[9];
    const float* bd  = (const float*)d_in[10];

    char* ws = (char*)d_ws;
    size_t off = 0;
    auto alloc = [&](size_t bytes) -> void* {
        void* p = ws + off;
        off += (bytes + 255) & ~(size_t)255;
        return p;
    };
    float* sq = (float*)alloc((size_t)NROWS * 4);
    unsigned long long* part =
        (unsigned long long*)alloc((size_t)NROWS * C_CHUNKS * KNN * 8);   // 20 MB
    int* knn = (int*)alloc((size_t)NROWS * KNN * 4);
    float* h1 = (float*)alloc((size_t)NROWS * H1C * 4);
    float* h2 = (float*)alloc((size_t)NROWS * H2C * 4);
    float* stats = (float*)alloc(4096);
    float* pmax = (float*)alloc(8 * 8 * 64 * 4);
    float* pmin = (float*)alloc(8 * 8 * 64 * 4);
    float* pooled = (float*)alloc(8 * 64 * 4);

    float* sum1 = stats,       *sumsq1 = stats + 32, *a1 = stats + 64,  *c1 = stats + 96;
    float* sum2 = stats + 128, *sumsq2 = stats + 192, *a2 = stats + 256, *c2 = stats + 320;

    hipMemsetAsync(stats, 0, 4096, stream);

    sq_kernel<<<NROWS / 256, 256, 0, stream>>>(x, sq);
    knn_partial<<<dim3(NROWS / 256, C_CHUNKS), 256, 0, stream>>>(x, sq, part);
    knn_merge<<<NROWS / 256, 256, 0, stream>>>(part, knn);
    edge_mlp1<<<NROWS / 4, 256, 0, stream>>>(x, knn, w1, b1, h1);
    stats_kernel<H1C><<<64, 256, 0, stream>>>(h1, sum1, sumsq1);
    coeff_kernel<H1C><<<1, 32, 0, stream>>>(sum1, sumsq1, g1, be1, a1, c1);
    mlp2_kernel<<<NROWS / 4, 256, 0, stream>>>(h1, w2, b2, a1, c1, h2);
    stats_kernel<H2C><<<64, 256, 0, stream>>>(h2, sum2, sumsq2);
    coeff_kernel<H2C><<<1, 64, 0, stream>>>(sum2, sumsq2, g2, be2, a2, c2);
    pool_part<<<64, 256, 0, stream>>>(h2, pmax, pmin);
    pool_final<<<8, 64, 0, stream>>>(pmax, pmin, a2, c2, pooled);
    head_kernel<<<8, 1024, 0, stream>>>(pooled, wd, bd, (float*)d_out);
}